// Round 7
// baseline (783.914 us; speedup 1.0000x reference)
//
#include <hip/hip_runtime.h>

// VGG16-A spiking NN, multi-compartment LIF (K=2), T=3, B=4, fp32.
// Round 13:
//  - r12 post-mortem: LDS halo staging made L4-L6 WORSE (96us, 7M bank
//    conflicts, VALU busy on staging index math + 1 barrier/round).
//  - L1-L3: reverted to r11 gathered conv_mid3 (known-good).
//  - L4-L6 (8x8 planes): NEW conv8_3_kernel — wave IS the plane (64 lanes
//    = 64 px). Per (ic,t): ONE coalesced plane load + 8 __shfl (DS pipe,
//    parallel to VALU) + cndmask boundary + 9*OCT FMA. No LDS staging,
//    no per-round barrier, no index division. Weights lane-uniform (SGPR).
//  - Everything else unchanged from r11 (671us baseline structure).

#define BATCH 4

__device__ __forceinline__ float lif_update(float mem_in, float syn, float thr,
                                            float leak, float* mem_out) {
    float m = leak * mem_in + syn;
    float val = 0.f;
    if ((m / thr - 1.f > 0.f) && (1.f - m / (2.f * thr) >= 0.f)) val += 1.f;
    if ((m / (2.f * thr) - 1.f > 0.f) && (1.f - m / (4.f * thr) >= 0.f)) val += 2.f;
    *mem_out = m - thr * val;
    return val;
}

// Layer 0: conv(x,w0) computed once (timestep-invariant), 3 LIF steps in
// registers, 3 spike outputs.
__global__ void conv_lif0_kernel(const float* __restrict__ in,
                                 const float* __restrict__ w,
                                 float* __restrict__ out0,
                                 float* __restrict__ out1,
                                 float* __restrict__ out2,
                                 const float* __restrict__ thr_v,
                                 const float* __restrict__ leak_v,
                                 int IC, int OC, int H, int W, int n) {
    int idx = blockIdx.x * blockDim.x + threadIdx.x;
    if (idx >= n) return;
    int x  = idx % W;
    int y  = (idx / W) % H;
    int oc = (idx / (W * H)) % OC;
    int b  = idx / (W * H * OC);

    const float* wp = w + (size_t)oc * IC * 9;
    const float* ip = in + (size_t)b * IC * H * W;

    float syn = 0.f;
    for (int ic = 0; ic < IC; ++ic) {
        const float* ipc = ip + (size_t)ic * H * W;
        const float* wpc = wp + ic * 9;
#pragma unroll
        for (int ky = 0; ky < 3; ++ky) {
            int yy = y + ky - 1;
            if (yy < 0 || yy >= H) continue;
#pragma unroll
            for (int kx = 0; kx < 3; ++kx) {
                int xx = x + kx - 1;
                if (xx < 0 || xx >= W) continue;
                syn = fmaf(ipc[yy * W + xx], wpc[ky * 3 + kx], syn);
            }
        }
    }
    float thr = thr_v[0], leak = leak_v[0];
    float m = 0.f;
    float v0 = lif_update(m, syn, thr, leak, &m);
    float v1 = lif_update(m, syn, thr, leak, &m);
    float v2 = lif_update(m, syn, thr, leak, &m);
    out0[idx] = v0;
    out1[idx] = v1;
    out2[idx] = v2;
}

// ---- conv_mid helpers ----
__device__ __forceinline__ void mid_load(float v[9], const float* __restrict__ ip,
                                         const int off[9], const bool msk[9]) {
#pragma unroll
    for (int k = 0; k < 9; ++k) v[k] = msk[k] ? ip[off[k]] : 0.f;
}

template <int OCT>
__device__ __forceinline__ void mid_fma(const float v[9], const float* __restrict__ wp,
                                        int IC, float acc[OCT]) {
#pragma unroll
    for (int t = 0; t < OCT; ++t) {
        const float* wt = wp + (size_t)t * IC * 9;
#pragma unroll
        for (int k = 0; k < 9; ++k) acc[t] = fmaf(v[k], wt[k], acc[t]);
    }
}

// Layers 1-3 (32x32 / 16x16 planes), 3 timesteps fused, gathered loads
// (r11-verified). Block = NW waves. blockIdx -> (b, chunk, oc-group).
template <int OCT, int NW, int POOL>
__global__ __launch_bounds__(NW * 64)
void conv_mid3_kernel(const float* __restrict__ in0,
                      const float* __restrict__ in1,
                      const float* __restrict__ in2,
                      const float* __restrict__ w,
                      float* __restrict__ out0,
                      float* __restrict__ out1,
                      float* __restrict__ out2,
                      const float* __restrict__ thr_v,
                      const float* __restrict__ leak_v,
                      int layer, int IC, int OC, int H, int W) {
    int tid = threadIdx.x;
    int lane = tid & 63;
    int wv = tid >> 6;  // 0..NW-1
    int ocg = OC / OCT;
    int HW = H * W;
    int chunks = HW >> 6;
    int bid = blockIdx.x;
    int g  = bid % ocg;
    int ch = (bid / ocg) % chunks;
    int b  = bid / (ocg * chunks);
    int rpw = 64 / W;
    int y = ch * rpw + lane / W;
    int x = lane % W;
    int oc0 = g * OCT;

    int off[9];
    bool msk[9];
#pragma unroll
    for (int ky = 0; ky < 3; ++ky)
#pragma unroll
        for (int kx = 0; kx < 3; ++kx) {
            int yy = y + ky - 1, xx = x + kx - 1;
            bool v = (yy >= 0 && yy < H && xx >= 0 && xx < W);
            msk[ky * 3 + kx] = v;
            off[ky * 3 + kx] = v ? yy * W + xx : 0;
        }

    size_t boff = (size_t)b * IC * HW;
    const float* ib[3] = {in0 + boff, in1 + boff, in2 + boff};
    float* const outs[3] = {out0, out1, out2};
    const float* wbase = w + (size_t)oc0 * IC * 9;

    float acc[3][OCT];
#pragma unroll
    for (int t = 0; t < 3; ++t)
#pragma unroll
        for (int q = 0; q < OCT; ++q) acc[t][q] = 0.f;

    int icpw = IC / NW;
    int ic0 = wv * icpw;
    int icend = ic0 + icpw;

    float vc[3][9];
#pragma unroll
    for (int t = 0; t < 3; ++t) mid_load(vc[t], ib[t] + (size_t)ic0 * HW, off, msk);

    for (int ic = ic0; ic < icend; ++ic) {
        int icn = (ic + 1 < icend) ? ic + 1 : ic;
        const float* wp = wbase + (size_t)ic * 9;
        float nv[3][9];
#pragma unroll
        for (int t = 0; t < 3; ++t) {
            mid_load(nv[t], ib[t] + (size_t)icn * HW, off, msk);
            mid_fma<OCT>(vc[t], wp, IC, acc[t]);
        }
#pragma unroll
        for (int t = 0; t < 3; ++t)
#pragma unroll
            for (int k = 0; k < 9; ++k) vc[t][k] = nv[t][k];
    }

    __shared__ float red[NW][OCT][64];
    __shared__ float vals[OCT][64];
    float thr = thr_v[layer], leak = leak_v[layer];
    float mem_reg = 0.f;  // membrane carried in-register across timesteps
    int eq = tid >> 6, ep = tid & 63;
    int Wo = W >> 1, Ho = H >> 1;

#pragma unroll
    for (int t = 0; t < 3; ++t) {
        __syncthreads();
#pragma unroll
        for (int q = 0; q < OCT; ++q) red[wv][q][lane] = acc[t][q];
        __syncthreads();
        if (tid < OCT * 64) {
            float sum = 0.f;
#pragma unroll
            for (int q = 0; q < NW; ++q) sum += red[q][eq][ep];
            float val = lif_update(mem_reg, sum, thr, leak, &mem_reg);
            if (POOL) {
                vals[eq][ep] = val;
            } else {
                size_t idx = (size_t)(b * OC + oc0 + eq) * HW + ch * 64 + ep;
                outs[t][idx] = val;
            }
        }
        if (POOL) {
            __syncthreads();
            if (tid < OCT * 16) {
                int q = tid >> 4, s = tid & 15;
                int pr = s / Wo, pc = s % Wo;
                float pv = 0.25f * (vals[q][(2 * pr) * W + 2 * pc] +
                                    vals[q][(2 * pr) * W + 2 * pc + 1] +
                                    vals[q][(2 * pr + 1) * W + 2 * pc] +
                                    vals[q][(2 * pr + 1) * W + 2 * pc + 1]);
                size_t pidx = ((size_t)(b * OC + oc0 + q) * Ho +
                               (ch * (rpw >> 1) + pr)) * Wo + pc;
                outs[t][pidx] = pv;
            }
        }
    }
}

// Layers 4-6 (8x8 planes): wave = plane (64 lanes = 64 px). Per (ic,t):
// ONE coalesced plane load; 9 taps via __shfl within the wave (DS pipe);
// boundary via cndmask; 9*OCT FMA. blockIdx -> (b, oc-group).
template <int OCT, int NW, int POOL>
__global__ __launch_bounds__(NW * 64)
void conv8_3_kernel(const float* __restrict__ in0,
                    const float* __restrict__ in1,
                    const float* __restrict__ in2,
                    const float* __restrict__ w,
                    float* __restrict__ out0,
                    float* __restrict__ out1,
                    float* __restrict__ out2,
                    const float* __restrict__ thr_v,
                    const float* __restrict__ leak_v,
                    int layer, int IC, int OC) {
    constexpr int HW = 64;  // 8x8 plane
    int tid = threadIdx.x;
    int lane = tid & 63;
    int wv = tid >> 6;  // 0..NW-1
    int ocg = OC / OCT;
    int bid = blockIdx.x;
    int g = bid % ocg;
    int b = bid / ocg;
    int oc0 = g * OCT;
    int y = lane >> 3, x = lane & 7;

    // tap source lanes + validity (src=lane when invalid; selected to 0)
    int srcl[9];
    bool v9[9];
#pragma unroll
    for (int ky = 0; ky < 3; ++ky)
#pragma unroll
        for (int kx = 0; kx < 3; ++kx) {
            int yy = y + ky - 1, xx = x + kx - 1;
            bool v = (yy >= 0 && yy < 8 && xx >= 0 && xx < 8);
            v9[ky * 3 + kx] = v;
            srcl[ky * 3 + kx] = v ? (yy * 8 + xx) : lane;
        }

    size_t boff = (size_t)b * IC * HW;
    const float* i0 = in0 + boff;
    const float* i1 = in1 + boff;
    const float* i2 = in2 + boff;
    float* const outs[3] = {out0, out1, out2};
    const float* wbase = w + (size_t)oc0 * IC * 9;

    float acc[3][OCT];
#pragma unroll
    for (int t = 0; t < 3; ++t)
#pragma unroll
        for (int q = 0; q < OCT; ++q) acc[t][q] = 0.f;

    int icpw = IC / NW;
    int ic0 = wv * icpw;
    int icend = ic0 + icpw;

    // 2-deep plane prefetch
    float p0 = i0[(size_t)ic0 * HW + lane];
    float p1 = i1[(size_t)ic0 * HW + lane];
    float p2 = i2[(size_t)ic0 * HW + lane];

    for (int ic = ic0; ic < icend; ++ic) {
        int icn = (ic + 1 < icend) ? ic + 1 : ic;
        float n0 = i0[(size_t)icn * HW + lane];
        float n1 = i1[(size_t)icn * HW + lane];
        float n2 = i2[(size_t)icn * HW + lane];

        const float* wp = wbase + (size_t)ic * 9;  // lane-uniform -> SGPR
        float wvv[OCT][9];
#pragma unroll
        for (int q = 0; q < OCT; ++q) {
            const float* wq = wp + (size_t)q * IC * 9;
#pragma unroll
            for (int k = 0; k < 9; ++k) wvv[q][k] = wq[k];
        }

#pragma unroll
        for (int k = 0; k < 9; ++k) {
            float t0 = __shfl(p0, srcl[k]);
            float t1 = __shfl(p1, srcl[k]);
            float t2 = __shfl(p2, srcl[k]);
            t0 = v9[k] ? t0 : 0.f;
            t1 = v9[k] ? t1 : 0.f;
            t2 = v9[k] ? t2 : 0.f;
#pragma unroll
            for (int q = 0; q < OCT; ++q) {
                acc[0][q] = fmaf(t0, wvv[q][k], acc[0][q]);
                acc[1][q] = fmaf(t1, wvv[q][k], acc[1][q]);
                acc[2][q] = fmaf(t2, wvv[q][k], acc[2][q]);
            }
        }
        p0 = n0; p1 = n1; p2 = n2;
    }

    __shared__ float red[NW][OCT][64];
    __shared__ float vals[OCT][64];
    float thr = thr_v[layer], leak = leak_v[layer];
    float mem_reg = 0.f;
    int eq = tid >> 6, ep = tid & 63;

#pragma unroll
    for (int t = 0; t < 3; ++t) {
        __syncthreads();
#pragma unroll
        for (int q = 0; q < OCT; ++q) red[wv][q][lane] = acc[t][q];
        __syncthreads();
        if (tid < OCT * 64) {
            float sum = 0.f;
#pragma unroll
            for (int q = 0; q < NW; ++q) sum += red[q][eq][ep];
            float val = lif_update(mem_reg, sum, thr, leak, &mem_reg);
            if (POOL) {
                vals[eq][ep] = val;
            } else {
                size_t idx = (size_t)(b * OC + oc0 + eq) * HW + ep;
                outs[t][idx] = val;
            }
        }
        if (POOL) {
            __syncthreads();
            if (tid < OCT * 16) {
                int q = tid >> 4, s = tid & 15;
                int pr = s >> 2, pc = s & 3;
                float pv = 0.25f * (vals[q][(2 * pr) * 8 + 2 * pc] +
                                    vals[q][(2 * pr) * 8 + 2 * pc + 1] +
                                    vals[q][(2 * pr + 1) * 8 + 2 * pc] +
                                    vals[q][(2 * pr + 1) * 8 + 2 * pc + 1]);
                size_t pidx = ((size_t)(b * OC + oc0 + q) * 4 + pr) * 4 + pc;
                outs[t][pidx] = pv;
            }
        }
    }
}

// Layers 7-12 (4x4 / 2x2 planes), 3 timesteps fused (sequential passes,
// membrane in-register). Block = NW waves, one oc per block.
template <int S, int NW, int POOL>
__global__ __launch_bounds__(NW * 64)
void conv_small4_3_kernel(const float* __restrict__ in0,
                          const float* __restrict__ in1,
                          const float* __restrict__ in2,
                          const float* __restrict__ w,
                          float* __restrict__ out0,
                          float* __restrict__ out1,
                          float* __restrict__ out2,
                          const float* __restrict__ thr_v,
                          const float* __restrict__ leak_v,
                          int layer, int IC, int OC) {
    constexpr int SS = S * S;
    constexpr int M = 4 * SS;              // 64 (S=4) or 16 (S=2)
    constexpr int LOG2M = (S == 4) ? 6 : 4;
    int tid = threadIdx.x;
    int lane = tid & 63;
    int wv = tid >> 6;  // 0..NW-1
    int oc = blockIdx.x;

    const float* const ins[3] = {in0, in1, in2};
    float* const outs[3] = {out0, out1, out2};
    const float* wrow = w + (size_t)oc * IC * 9;

    __shared__ float red[NW][M];
    __shared__ float pvs[M];
    float thr = thr_v[layer], leak = leak_v[layer];
    float mem_reg = 0.f;  // for tid < M

#pragma unroll
    for (int t = 0; t < 3; ++t) {
        const float* inb = ins[t];
        float acc[M];
#pragma unroll
        for (int i = 0; i < M; ++i) acc[i] = 0.f;

        for (int ic = lane + (wv << 6); ic < IC; ic += NW * 64) {
            const float* wp = wrow + (size_t)ic * 9;
            float wvv[9];
#pragma unroll
            for (int k = 0; k < 9; ++k) wvv[k] = wp[k];
#pragma unroll
            for (int b = 0; b < 4; ++b) {
                const float4* ip = (const float4*)(inb + (size_t)(b * IC + ic) * SS);
                float pv[SS];
#pragma unroll
                for (int q = 0; q < SS / 4; ++q) {
                    float4 t4 = ip[q];
                    pv[4 * q + 0] = t4.x;
                    pv[4 * q + 1] = t4.y;
                    pv[4 * q + 2] = t4.z;
                    pv[4 * q + 3] = t4.w;
                }
#pragma unroll
                for (int y = 0; y < S; ++y)
#pragma unroll
                    for (int x = 0; x < S; ++x) {
                        float a = acc[b * SS + y * S + x];
#pragma unroll
                        for (int ky = 0; ky < 3; ++ky) {
                            int yy = y + ky - 1;
                            if (yy < 0 || yy >= S) continue;
#pragma unroll
                            for (int kx = 0; kx < 3; ++kx) {
                                int xx = x + kx - 1;
                                if (xx < 0 || xx >= S) continue;
                                a = fmaf(pv[yy * S + xx], wvv[ky * 3 + kx], a);
                            }
                        }
                        acc[b * SS + y * S + x] = a;
                    }
            }
        }

        // per-wave transpose-reduce: M accs across 64 lanes -> 1 per lane
#pragma unroll
        for (int step = 0; step < LOG2M; ++step) {
            const int offx = 1 << step;
            const int half = M >> (step + 1);
            const bool hi = (lane & offx) != 0;
#pragma unroll
            for (int i = 0; i < half; ++i) {
                float sent = hi ? acc[i] : acc[i + half];
                float got = __shfl_xor(sent, offx);
                acc[i] = (hi ? acc[i + half] : acc[i]) + got;
            }
        }
        float sum = acc[0];
#pragma unroll
        for (int offx = M; offx < 64; offx <<= 1) sum += __shfl_xor(sum, offx);

        __syncthreads();  // protect red/pvs from previous timestep's readers
        int o = (int)(__brev((unsigned)(lane & (M - 1))) >> (32 - LOG2M));
        if (lane < M) red[wv][o] = sum;
        __syncthreads();

        if (tid < M) {
            float tot = 0.f;
#pragma unroll
            for (int q = 0; q < NW; ++q) tot += red[q][tid];
            int b = tid / SS, p = tid % SS;
            float val = lif_update(mem_reg, tot, thr_v[layer], leak, &mem_reg);
            if (POOL) {
                pvs[tid] = val;
            } else {
                size_t idx = (size_t)(b * OC + oc) * SS + p;
                outs[t][idx] = val;
            }
        }
        if (POOL) {
            __syncthreads();
            constexpr int Sh = S / 2, SSh = Sh * Sh;
            if (tid < 4 * SSh) {
                int b = tid / SSh, q = tid % SSh;
                int pr = q / Sh, pc = q % Sh;
                float pv = 0.25f * (pvs[b * SS + (2 * pr) * S + 2 * pc] +
                                    pvs[b * SS + (2 * pr) * S + 2 * pc + 1] +
                                    pvs[b * SS + (2 * pr + 1) * S + 2 * pc] +
                                    pvs[b * SS + (2 * pr + 1) * S + 2 * pc + 1]);
                outs[t][((size_t)(b * OC + oc) * Sh + pr) * Sh + pc] = pv;
            }
        }
    }
}

// Wave-per-output-neuron FC+LIF, 3 timesteps fused: weight row read ONCE,
// 12 accumulators (3t x 4b), membrane chain at lane 0.
__global__ void fc_lif3_kernel(const float* __restrict__ in0,
                               const float* __restrict__ in1,
                               const float* __restrict__ in2,
                               const float* __restrict__ w,
                               float* __restrict__ out0,
                               float* __restrict__ out1,
                               float* __restrict__ out2,
                               const float* __restrict__ thr_v,
                               const float* __restrict__ leak_v,
                               int layer, int Kd, int N) {
    int wave = (blockIdx.x * blockDim.x + threadIdx.x) >> 6;
    int lane = threadIdx.x & 63;
    if (wave >= N) return;
    int j = wave;
    int K4 = Kd >> 2;
    const float4* wp = (const float4*)(w + (size_t)j * Kd);
    const float4* ip[3] = {(const float4*)in0, (const float4*)in1, (const float4*)in2};
    float* const outs[3] = {out0, out1, out2};

    float a[3][4];
#pragma unroll
    for (int t = 0; t < 3; ++t)
#pragma unroll
        for (int b = 0; b < 4; ++b) a[t][b] = 0.f;

    for (int k = lane; k < K4; k += 64) {
        float4 wv = wp[k];
#pragma unroll
        for (int t = 0; t < 3; ++t)
#pragma unroll
            for (int b = 0; b < 4; ++b) {
                float4 v = ip[t][b * K4 + k];
                a[t][b] = fmaf(wv.x, v.x, fmaf(wv.y, v.y,
                          fmaf(wv.z, v.z, fmaf(wv.w, v.w, a[t][b]))));
            }
    }
#pragma unroll
    for (int t = 0; t < 3; ++t)
#pragma unroll
        for (int b = 0; b < 4; ++b)
#pragma unroll
            for (int off = 32; off > 0; off >>= 1)
                a[t][b] += __shfl_xor(a[t][b], off);

    if (lane == 0) {
        float thr = thr_v[layer], leak = leak_v[layer];
#pragma unroll
        for (int b = 0; b < BATCH; ++b) {
            float m = 0.f;
#pragma unroll
            for (int t = 0; t < 3; ++t) {
                float val = lif_update(m, a[t][b], thr, leak, &m);
                outs[t][(size_t)b * N + j] = val;
            }
        }
    }
}

// One 64-thread block per (b, label). logits = sum_t in_t[b,:] . w[l,:]
__global__ void fc2_acc3_kernel(const float* __restrict__ in0,
                                const float* __restrict__ in1,
                                const float* __restrict__ in2,
                                const float* __restrict__ w,
                                float* __restrict__ logits,
                                int Kd, int L) {
    int o = blockIdx.x;
    int l = o % L;
    int b = o / L;
    int K4 = Kd >> 2;
    const float4* ip[3] = {(const float4*)(in0 + (size_t)b * Kd),
                           (const float4*)(in1 + (size_t)b * Kd),
                           (const float4*)(in2 + (size_t)b * Kd)};
    const float4* wp = (const float4*)(w + (size_t)l * Kd);
    float st[3] = {0.f, 0.f, 0.f};
    for (int k = threadIdx.x; k < K4; k += 64) {
        float4 wv = wp[k];
#pragma unroll
        for (int t = 0; t < 3; ++t) {
            float4 iv = ip[t][k];
            st[t] = fmaf(iv.x, wv.x, fmaf(iv.y, wv.y,
                    fmaf(iv.z, wv.z, fmaf(iv.w, wv.w, st[t]))));
        }
    }
#pragma unroll
    for (int t = 0; t < 3; ++t)
#pragma unroll
        for (int off = 32; off > 0; off >>= 1) st[t] += __shfl_xor(st[t], off);
    if (threadIdx.x == 0) logits[o] = (st[0] + st[1]) + st[2];
}

extern "C" void kernel_launch(void* const* d_in, const int* in_sizes, int n_in,
                              void* d_out, int out_size, void* d_ws, size_t ws_size,
                              hipStream_t stream) {
    const float* x = (const float*)d_in[0];
    const float* convw[13];
    for (int i = 0; i < 13; ++i) convw[i] = (const float*)d_in[1 + i];
    const float* fc0 = (const float*)d_in[14];
    const float* fc1 = (const float*)d_in[15];
    const float* fc2 = (const float*)d_in[16];
    const float* thr = (const float*)d_in[17];
    const float* leak = (const float*)d_in[18];

    static const int IC[13] = {3, 64, 64, 128, 128, 256, 256, 256, 512, 512, 512, 512, 512};
    static const int OC[13] = {64, 64, 128, 128, 256, 256, 256, 512, 512, 512, 512, 512, 512};

    float* ws = (float*)d_ws;
    // two ping-pong sets of 3 timestep buffers, 262144 floats each
    float* A[3];
    float* B[3];
    size_t off = 0;
    for (int i = 0; i < 3; ++i) { A[i] = ws + off; off += 262144; }
    for (int i = 0; i < 3; ++i) { B[i] = ws + off; off += 262144; }

    // L0: conv once + 3 in-register LIF steps -> A
    {
        int n = BATCH * 64 * 32 * 32;
        conv_lif0_kernel<<<(n + 255) / 256, 256, 0, stream>>>(
            x, convw[0], A[0], A[1], A[2], thr, leak, 3, 64, 32, 32, n);
    }

    float** src = A;
    float** dst = B;

    // L1: 64->64 @32x32, pool. blocks = 4 * 16 * 16 = 1024
    conv_mid3_kernel<4, 8, 1><<<BATCH * 16 * (OC[1] / 4), 512, 0, stream>>>(
        src[0], src[1], src[2], convw[1], dst[0], dst[1], dst[2],
        thr, leak, 1, IC[1], OC[1], 32, 32);
    { float** tmp = src; src = dst; dst = tmp; }

    // L2: 64->128 @16x16. blocks = 4 * 4 * 32 = 512
    conv_mid3_kernel<4, 8, 0><<<BATCH * 4 * (OC[2] / 4), 512, 0, stream>>>(
        src[0], src[1], src[2], convw[2], dst[0], dst[1], dst[2],
        thr, leak, 2, IC[2], OC[2], 16, 16);
    { float** tmp = src; src = dst; dst = tmp; }

    // L3: 128->128 @16x16, pool. blocks = 512
    conv_mid3_kernel<4, 8, 1><<<BATCH * 4 * (OC[3] / 4), 512, 0, stream>>>(
        src[0], src[1], src[2], convw[3], dst[0], dst[1], dst[2],
        thr, leak, 3, IC[3], OC[3], 16, 16);
    { float** tmp = src; src = dst; dst = tmp; }

    // L4: 128->256 @8x8. blocks = 4 * 128 = 512
    conv8_3_kernel<2, 8, 0><<<BATCH * (OC[4] / 2), 512, 0, stream>>>(
        src[0], src[1], src[2], convw[4], dst[0], dst[1], dst[2],
        thr, leak, 4, IC[4], OC[4]);
    { float** tmp = src; src = dst; dst = tmp; }

    // L5: 256->256 @8x8. blocks = 512
    conv8_3_kernel<2, 8, 0><<<BATCH * (OC[5] / 2), 512, 0, stream>>>(
        src[0], src[1], src[2], convw[5], dst[0], dst[1], dst[2],
        thr, leak, 5, IC[5], OC[5]);
    { float** tmp = src; src = dst; dst = tmp; }

    // L6: 256->256 @8x8, pool. blocks = 512
    conv8_3_kernel<2, 8, 1><<<BATCH * (OC[6] / 2), 512, 0, stream>>>(
        src[0], src[1], src[2], convw[6], dst[0], dst[1], dst[2],
        thr, leak, 6, IC[6], OC[6]);
    { float** tmp = src; src = dst; dst = tmp; }

    // L7-L12: conv_small4_3
    for (int i = 7; i <= 12; ++i) {
        if (i == 7)
            conv_small4_3_kernel<4, 4, 0><<<OC[i], 256, 0, stream>>>(
                src[0], src[1], src[2], convw[i], dst[0], dst[1], dst[2],
                thr, leak, i, IC[i], OC[i]);
        else if (i == 8)
            conv_small4_3_kernel<4, 8, 0><<<OC[i], 512, 0, stream>>>(
                src[0], src[1], src[2], convw[i], dst[0], dst[1], dst[2],
                thr, leak, i, IC[i], OC[i]);
        else if (i == 9)
            conv_small4_3_kernel<4, 8, 1><<<OC[i], 512, 0, stream>>>(
                src[0], src[1], src[2], convw[i], dst[0], dst[1], dst[2],
                thr, leak, i, IC[i], OC[i]);
        else
            conv_small4_3_kernel<2, 8, 0><<<OC[i], 512, 0, stream>>>(
                src[0], src[1], src[2], convw[i], dst[0], dst[1], dst[2],
                thr, leak, i, IC[i], OC[i]);
        float** tmp = src; src = dst; dst = tmp;
    }

    // fc0, fc1 (LIF), fc2 (logit accumulate over t)
    fc_lif3_kernel<<<(4096 * 64) / 256, 256, 0, stream>>>(
        src[0], src[1], src[2], fc0, dst[0], dst[1], dst[2],
        thr, leak, 13, 2048, 4096);
    { float** tmp = src; src = dst; dst = tmp; }

    fc_lif3_kernel<<<(4096 * 64) / 256, 256, 0, stream>>>(
        src[0], src[1], src[2], fc1, dst[0], dst[1], dst[2],
        thr, leak, 14, 4096, 4096);
    { float** tmp = src; src = dst; dst = tmp; }

    fc2_acc3_kernel<<<BATCH * 10, 64, 0, stream>>>(
        src[0], src[1], src[2], fc2, (float*)d_out, 4096, 10);
}

// Round 8
// 692.164 us; speedup vs baseline: 1.1326x; 1.1326x over previous
//
#include <hip/hip_runtime.h>

// VGG16-A spiking NN, multi-compartment LIF (K=2), T=3, B=4, fp32.
// Round 14:
//  - r13 post-mortem: conv8_3 (shuffle stencil) regressed L4-L6; reverted.
//    Top dispatch was L1 all along (FETCH 12.4MB / WRITE 768KB signature).
//  - Real stall in conv_mid3: weights loaded from GLOBAL inside the ic
//    loop, un-prefetched -> 200-400cy exposed every iteration.
//  - Fix 1: block's OCT x IC x 9 weight slab staged to LDS ONCE (linear
//    cooperative copy, one barrier); inner loop reads weights via
//    wave-uniform ds_read (broadcast, DS pipe overlaps VALU).
//  - Fix 2: ping-pong va/vb input regs (step-2 loop) — no 27-mov copies.
//  - Fix 3: L1 OCT 4->8 (halves 16x input re-gather redundancy).
//  - IC/W are template params: compile-time loop bounds.

#define BATCH 4

__device__ __forceinline__ float lif_update(float mem_in, float syn, float thr,
                                            float leak, float* mem_out) {
    float m = leak * mem_in + syn;
    float val = 0.f;
    if ((m / thr - 1.f > 0.f) && (1.f - m / (2.f * thr) >= 0.f)) val += 1.f;
    if ((m / (2.f * thr) - 1.f > 0.f) && (1.f - m / (4.f * thr) >= 0.f)) val += 2.f;
    *mem_out = m - thr * val;
    return val;
}

// Layer 0: conv(x,w0) computed once (timestep-invariant), 3 LIF steps in
// registers, 3 spike outputs.
__global__ void conv_lif0_kernel(const float* __restrict__ in,
                                 const float* __restrict__ w,
                                 float* __restrict__ out0,
                                 float* __restrict__ out1,
                                 float* __restrict__ out2,
                                 const float* __restrict__ thr_v,
                                 const float* __restrict__ leak_v,
                                 int IC, int OC, int H, int W, int n) {
    int idx = blockIdx.x * blockDim.x + threadIdx.x;
    if (idx >= n) return;
    int x  = idx % W;
    int y  = (idx / W) % H;
    int oc = (idx / (W * H)) % OC;
    int b  = idx / (W * H * OC);

    const float* wp = w + (size_t)oc * IC * 9;
    const float* ip = in + (size_t)b * IC * H * W;

    float syn = 0.f;
    for (int ic = 0; ic < IC; ++ic) {
        const float* ipc = ip + (size_t)ic * H * W;
        const float* wpc = wp + ic * 9;
#pragma unroll
        for (int ky = 0; ky < 3; ++ky) {
            int yy = y + ky - 1;
            if (yy < 0 || yy >= H) continue;
#pragma unroll
            for (int kx = 0; kx < 3; ++kx) {
                int xx = x + kx - 1;
                if (xx < 0 || xx >= W) continue;
                syn = fmaf(ipc[yy * W + xx], wpc[ky * 3 + kx], syn);
            }
        }
    }
    float thr = thr_v[0], leak = leak_v[0];
    float m = 0.f;
    float v0 = lif_update(m, syn, thr, leak, &m);
    float v1 = lif_update(m, syn, thr, leak, &m);
    float v2 = lif_update(m, syn, thr, leak, &m);
    out0[idx] = v0;
    out1[idx] = v1;
    out2[idx] = v2;
}

// ---- conv_mid helpers ----
__device__ __forceinline__ void mid_load3(float v[3][9],
                                          const float* __restrict__ p0,
                                          const float* __restrict__ p1,
                                          const float* __restrict__ p2,
                                          const int off[9], const bool msk[9]) {
#pragma unroll
    for (int k = 0; k < 9; ++k) {
        v[0][k] = msk[k] ? p0[off[k]] : 0.f;
        v[1][k] = msk[k] ? p1[off[k]] : 0.f;
        v[2][k] = msk[k] ? p2[off[k]] : 0.f;
    }
}

// FMA all 3 timesteps for one ic, weights from LDS (wave-uniform ds_read).
template <int OCT, int ICT>
__device__ __forceinline__ void mid_fma3(const float v[3][9],
                                         const float* __restrict__ wlds,
                                         int ic, float acc[3][OCT]) {
#pragma unroll
    for (int q = 0; q < OCT; ++q) {
        const float* wq = wlds + ((size_t)q * ICT + ic) * 9;
        float wr[9];
#pragma unroll
        for (int k = 0; k < 9; ++k) wr[k] = wq[k];
#pragma unroll
        for (int k = 0; k < 9; ++k) {
            acc[0][q] = fmaf(v[0][k], wr[k], acc[0][q]);
            acc[1][q] = fmaf(v[1][k], wr[k], acc[1][q]);
            acc[2][q] = fmaf(v[2][k], wr[k], acc[2][q]);
        }
    }
}

// Layers 1-6, 3 timesteps fused. Block = NW waves. blockIdx ->
// (b, chunk, oc-group). Weight slab in LDS (staged once); inputs gathered
// with ping-pong 2-deep prefetch; LDS reduce; in-register membrane LIF;
// optional fused pool. Requires (ICT/NW) even.
template <int OCT, int NW, int POOL, int ICT, int W_>
__global__ __launch_bounds__(NW * 64)
void conv_mid3_kernel(const float* __restrict__ in0,
                      const float* __restrict__ in1,
                      const float* __restrict__ in2,
                      const float* __restrict__ w,
                      float* __restrict__ out0,
                      float* __restrict__ out1,
                      float* __restrict__ out2,
                      const float* __restrict__ thr_v,
                      const float* __restrict__ leak_v,
                      int layer, int OC) {
    constexpr int HW = W_ * W_;
    constexpr int CHUNKS = HW / 64;
    constexpr int RPW = 64 / W_;
    constexpr int ICPW = ICT / NW;
    static_assert((ICPW & 1) == 0, "icpw must be even");

    int tid = threadIdx.x;
    int lane = tid & 63;
    int wv = tid >> 6;  // 0..NW-1
    int ocg = OC / OCT;
    int bid = blockIdx.x;
    int g  = bid % ocg;
    int ch = (bid / ocg) % CHUNKS;
    int b  = bid / (ocg * CHUNKS);
    int y = ch * RPW + lane / W_;
    int x = lane % W_;
    int oc0 = g * OCT;

    int off[9];
    bool msk[9];
#pragma unroll
    for (int ky = 0; ky < 3; ++ky)
#pragma unroll
        for (int kx = 0; kx < 3; ++kx) {
            int yy = y + ky - 1, xx = x + kx - 1;
            bool v = (yy >= 0 && yy < W_ && xx >= 0 && xx < W_);
            msk[ky * 3 + kx] = v;
            off[ky * 3 + kx] = v ? yy * W_ + xx : 0;
        }

    size_t boff = (size_t)b * ICT * HW;
    const float* i0 = in0 + boff;
    const float* i1 = in1 + boff;
    const float* i2 = in2 + boff;
    float* const outs[3] = {out0, out1, out2};

    // stage this block's weight slab to LDS (linear, coalesced, once)
    __shared__ float wlds[OCT * ICT * 9];
    {
        const float* wsrc = w + (size_t)oc0 * ICT * 9;
        for (int s = tid; s < OCT * ICT * 9; s += NW * 64) wlds[s] = wsrc[s];
    }
    __syncthreads();

    float acc[3][OCT];
#pragma unroll
    for (int t = 0; t < 3; ++t)
#pragma unroll
        for (int q = 0; q < OCT; ++q) acc[t][q] = 0.f;

    int ic0 = wv * ICPW;
    int icend = ic0 + ICPW;

    float va[3][9], vb[3][9];
    mid_load3(va, i0 + (size_t)ic0 * HW, i1 + (size_t)ic0 * HW,
              i2 + (size_t)ic0 * HW, off, msk);

    for (int ic = ic0; ic < icend; ic += 2) {
        // prefetch ic+1 while computing ic
        mid_load3(vb, i0 + (size_t)(ic + 1) * HW, i1 + (size_t)(ic + 1) * HW,
                  i2 + (size_t)(ic + 1) * HW, off, msk);
        mid_fma3<OCT, ICT>(va, wlds, ic, acc);
        // prefetch ic+2 (clamped dummy on last pair) while computing ic+1
        int icn = (ic + 2 < icend) ? ic + 2 : ic;
        mid_load3(va, i0 + (size_t)icn * HW, i1 + (size_t)icn * HW,
                  i2 + (size_t)icn * HW, off, msk);
        mid_fma3<OCT, ICT>(vb, wlds, ic + 1, acc);
    }

    __shared__ float red[NW][OCT][64];
    __shared__ float vals[OCT][64];
    float thr = thr_v[layer], leak = leak_v[layer];
    float mem_reg = 0.f;  // membrane carried in-register across timesteps
    int eq = tid >> 6, ep = tid & 63;
    constexpr int Wo = W_ / 2, Ho = W_ / 2;

#pragma unroll
    for (int t = 0; t < 3; ++t) {
        __syncthreads();
#pragma unroll
        for (int q = 0; q < OCT; ++q) red[wv][q][lane] = acc[t][q];
        __syncthreads();
        if (tid < OCT * 64) {
            float sum = 0.f;
#pragma unroll
            for (int q = 0; q < NW; ++q) sum += red[q][eq][ep];
            float val = lif_update(mem_reg, sum, thr, leak, &mem_reg);
            if (POOL) {
                vals[eq][ep] = val;
            } else {
                size_t idx = (size_t)(b * OC + oc0 + eq) * HW + ch * 64 + ep;
                outs[t][idx] = val;
            }
        }
        if (POOL) {
            __syncthreads();
            if (tid < OCT * 16) {
                int q = tid >> 4, s = tid & 15;
                int pr = s / Wo, pc = s % Wo;
                float pv = 0.25f * (vals[q][(2 * pr) * W_ + 2 * pc] +
                                    vals[q][(2 * pr) * W_ + 2 * pc + 1] +
                                    vals[q][(2 * pr + 1) * W_ + 2 * pc] +
                                    vals[q][(2 * pr + 1) * W_ + 2 * pc + 1]);
                size_t pidx = ((size_t)(b * OC + oc0 + q) * Ho +
                               (ch * (RPW >> 1) + pr)) * Wo + pc;
                outs[t][pidx] = pv;
            }
        }
    }
}

// Layers 7-12 (4x4 / 2x2 planes), 3 timesteps fused (sequential passes,
// membrane in-register). Block = NW waves, one oc per block.
template <int S, int NW, int POOL>
__global__ __launch_bounds__(NW * 64)
void conv_small4_3_kernel(const float* __restrict__ in0,
                          const float* __restrict__ in1,
                          const float* __restrict__ in2,
                          const float* __restrict__ w,
                          float* __restrict__ out0,
                          float* __restrict__ out1,
                          float* __restrict__ out2,
                          const float* __restrict__ thr_v,
                          const float* __restrict__ leak_v,
                          int layer, int IC, int OC) {
    constexpr int SS = S * S;
    constexpr int M = 4 * SS;              // 64 (S=4) or 16 (S=2)
    constexpr int LOG2M = (S == 4) ? 6 : 4;
    int tid = threadIdx.x;
    int lane = tid & 63;
    int wv = tid >> 6;  // 0..NW-1
    int oc = blockIdx.x;

    const float* const ins[3] = {in0, in1, in2};
    float* const outs[3] = {out0, out1, out2};
    const float* wrow = w + (size_t)oc * IC * 9;

    __shared__ float red[NW][M];
    __shared__ float pvs[M];
    float thr = thr_v[layer], leak = leak_v[layer];
    float mem_reg = 0.f;  // for tid < M

#pragma unroll
    for (int t = 0; t < 3; ++t) {
        const float* inb = ins[t];
        float acc[M];
#pragma unroll
        for (int i = 0; i < M; ++i) acc[i] = 0.f;

        for (int ic = lane + (wv << 6); ic < IC; ic += NW * 64) {
            const float* wp = wrow + (size_t)ic * 9;
            float wvv[9];
#pragma unroll
            for (int k = 0; k < 9; ++k) wvv[k] = wp[k];
#pragma unroll
            for (int b = 0; b < 4; ++b) {
                const float4* ip = (const float4*)(inb + (size_t)(b * IC + ic) * SS);
                float pv[SS];
#pragma unroll
                for (int q = 0; q < SS / 4; ++q) {
                    float4 t4 = ip[q];
                    pv[4 * q + 0] = t4.x;
                    pv[4 * q + 1] = t4.y;
                    pv[4 * q + 2] = t4.z;
                    pv[4 * q + 3] = t4.w;
                }
#pragma unroll
                for (int y = 0; y < S; ++y)
#pragma unroll
                    for (int x = 0; x < S; ++x) {
                        float a = acc[b * SS + y * S + x];
#pragma unroll
                        for (int ky = 0; ky < 3; ++ky) {
                            int yy = y + ky - 1;
                            if (yy < 0 || yy >= S) continue;
#pragma unroll
                            for (int kx = 0; kx < 3; ++kx) {
                                int xx = x + kx - 1;
                                if (xx < 0 || xx >= S) continue;
                                a = fmaf(pv[yy * S + xx], wvv[ky * 3 + kx], a);
                            }
                        }
                        acc[b * SS + y * S + x] = a;
                    }
            }
        }

        // per-wave transpose-reduce: M accs across 64 lanes -> 1 per lane
#pragma unroll
        for (int step = 0; step < LOG2M; ++step) {
            const int offx = 1 << step;
            const int half = M >> (step + 1);
            const bool hi = (lane & offx) != 0;
#pragma unroll
            for (int i = 0; i < half; ++i) {
                float sent = hi ? acc[i] : acc[i + half];
                float got = __shfl_xor(sent, offx);
                acc[i] = (hi ? acc[i + half] : acc[i]) + got;
            }
        }
        float sum = acc[0];
#pragma unroll
        for (int offx = M; offx < 64; offx <<= 1) sum += __shfl_xor(sum, offx);

        __syncthreads();  // protect red/pvs from previous timestep's readers
        int o = (int)(__brev((unsigned)(lane & (M - 1))) >> (32 - LOG2M));
        if (lane < M) red[wv][o] = sum;
        __syncthreads();

        if (tid < M) {
            float tot = 0.f;
#pragma unroll
            for (int q = 0; q < NW; ++q) tot += red[q][tid];
            int b = tid / SS, p = tid % SS;
            float val = lif_update(mem_reg, tot, thr, leak, &mem_reg);
            if (POOL) {
                pvs[tid] = val;
            } else {
                size_t idx = (size_t)(b * OC + oc) * SS + p;
                outs[t][idx] = val;
            }
        }
        if (POOL) {
            __syncthreads();
            constexpr int Sh = S / 2, SSh = Sh * Sh;
            if (tid < 4 * SSh) {
                int b = tid / SSh, q = tid % SSh;
                int pr = q / Sh, pc = q % Sh;
                float pv = 0.25f * (pvs[b * SS + (2 * pr) * S + 2 * pc] +
                                    pvs[b * SS + (2 * pr) * S + 2 * pc + 1] +
                                    pvs[b * SS + (2 * pr + 1) * S + 2 * pc] +
                                    pvs[b * SS + (2 * pr + 1) * S + 2 * pc + 1]);
                outs[t][((size_t)(b * OC + oc) * Sh + pr) * Sh + pc] = pv;
            }
        }
    }
}

// Wave-per-output-neuron FC+LIF, 3 timesteps fused: weight row read ONCE,
// 12 accumulators (3t x 4b), membrane chain at lane 0.
__global__ void fc_lif3_kernel(const float* __restrict__ in0,
                               const float* __restrict__ in1,
                               const float* __restrict__ in2,
                               const float* __restrict__ w,
                               float* __restrict__ out0,
                               float* __restrict__ out1,
                               float* __restrict__ out2,
                               const float* __restrict__ thr_v,
                               const float* __restrict__ leak_v,
                               int layer, int Kd, int N) {
    int wave = (blockIdx.x * blockDim.x + threadIdx.x) >> 6;
    int lane = threadIdx.x & 63;
    if (wave >= N) return;
    int j = wave;
    int K4 = Kd >> 2;
    const float4* wp = (const float4*)(w + (size_t)j * Kd);
    const float4* ip[3] = {(const float4*)in0, (const float4*)in1, (const float4*)in2};
    float* const outs[3] = {out0, out1, out2};

    float a[3][4];
#pragma unroll
    for (int t = 0; t < 3; ++t)
#pragma unroll
        for (int b = 0; b < 4; ++b) a[t][b] = 0.f;

    for (int k = lane; k < K4; k += 64) {
        float4 wv = wp[k];
#pragma unroll
        for (int t = 0; t < 3; ++t)
#pragma unroll
            for (int b = 0; b < 4; ++b) {
                float4 v = ip[t][b * K4 + k];
                a[t][b] = fmaf(wv.x, v.x, fmaf(wv.y, v.y,
                          fmaf(wv.z, v.z, fmaf(wv.w, v.w, a[t][b]))));
            }
    }
#pragma unroll
    for (int t = 0; t < 3; ++t)
#pragma unroll
        for (int b = 0; b < 4; ++b)
#pragma unroll
            for (int off = 32; off > 0; off >>= 1)
                a[t][b] += __shfl_xor(a[t][b], off);

    if (lane == 0) {
        float thr = thr_v[layer], leak = leak_v[layer];
#pragma unroll
        for (int b = 0; b < BATCH; ++b) {
            float m = 0.f;
#pragma unroll
            for (int t = 0; t < 3; ++t) {
                float val = lif_update(m, a[t][b], thr, leak, &m);
                outs[t][(size_t)b * N + j] = val;
            }
        }
    }
}

// One 64-thread block per (b, label). logits = sum_t in_t[b,:] . w[l,:]
__global__ void fc2_acc3_kernel(const float* __restrict__ in0,
                                const float* __restrict__ in1,
                                const float* __restrict__ in2,
                                const float* __restrict__ w,
                                float* __restrict__ logits,
                                int Kd, int L) {
    int o = blockIdx.x;
    int l = o % L;
    int b = o / L;
    int K4 = Kd >> 2;
    const float4* ip[3] = {(const float4*)(in0 + (size_t)b * Kd),
                           (const float4*)(in1 + (size_t)b * Kd),
                           (const float4*)(in2 + (size_t)b * Kd)};
    const float4* wp = (const float4*)(w + (size_t)l * Kd);
    float st[3] = {0.f, 0.f, 0.f};
    for (int k = threadIdx.x; k < K4; k += 64) {
        float4 wv = wp[k];
#pragma unroll
        for (int t = 0; t < 3; ++t) {
            float4 iv = ip[t][k];
            st[t] = fmaf(iv.x, wv.x, fmaf(iv.y, wv.y,
                    fmaf(iv.z, wv.z, fmaf(iv.w, wv.w, st[t]))));
        }
    }
#pragma unroll
    for (int t = 0; t < 3; ++t)
#pragma unroll
        for (int off = 32; off > 0; off >>= 1) st[t] += __shfl_xor(st[t], off);
    if (threadIdx.x == 0) logits[o] = (st[0] + st[1]) + st[2];
}

extern "C" void kernel_launch(void* const* d_in, const int* in_sizes, int n_in,
                              void* d_out, int out_size, void* d_ws, size_t ws_size,
                              hipStream_t stream) {
    const float* x = (const float*)d_in[0];
    const float* convw[13];
    for (int i = 0; i < 13; ++i) convw[i] = (const float*)d_in[1 + i];
    const float* fc0 = (const float*)d_in[14];
    const float* fc1 = (const float*)d_in[15];
    const float* fc2 = (const float*)d_in[16];
    const float* thr = (const float*)d_in[17];
    const float* leak = (const float*)d_in[18];

    static const int IC[13] = {3, 64, 64, 128, 128, 256, 256, 256, 512, 512, 512, 512, 512};
    static const int OC[13] = {64, 64, 128, 128, 256, 256, 256, 512, 512, 512, 512, 512, 512};

    float* ws = (float*)d_ws;
    // two ping-pong sets of 3 timestep buffers, 262144 floats each
    float* A[3];
    float* B[3];
    size_t off = 0;
    for (int i = 0; i < 3; ++i) { A[i] = ws + off; off += 262144; }
    for (int i = 0; i < 3; ++i) { B[i] = ws + off; off += 262144; }

    // L0: conv once + 3 in-register LIF steps -> A
    {
        int n = BATCH * 64 * 32 * 32;
        conv_lif0_kernel<<<(n + 255) / 256, 256, 0, stream>>>(
            x, convw[0], A[0], A[1], A[2], thr, leak, 3, 64, 32, 32, n);
    }

    float** src = A;
    float** dst = B;

    // L1: 64->64 @32x32, pool. OCT=8 -> blocks = 4*16*8 = 512
    conv_mid3_kernel<8, 8, 1, 64, 32><<<BATCH * 16 * (OC[1] / 8), 512, 0, stream>>>(
        src[0], src[1], src[2], convw[1], dst[0], dst[1], dst[2],
        thr, leak, 1, OC[1]);
    { float** tmp = src; src = dst; dst = tmp; }

    // L2: 64->128 @16x16. blocks = 4*4*32 = 512
    conv_mid3_kernel<4, 8, 0, 64, 16><<<BATCH * 4 * (OC[2] / 4), 512, 0, stream>>>(
        src[0], src[1], src[2], convw[2], dst[0], dst[1], dst[2],
        thr, leak, 2, OC[2]);
    { float** tmp = src; src = dst; dst = tmp; }

    // L3: 128->128 @16x16, pool. blocks = 512
    conv_mid3_kernel<4, 8, 1, 128, 16><<<BATCH * 4 * (OC[3] / 4), 512, 0, stream>>>(
        src[0], src[1], src[2], convw[3], dst[0], dst[1], dst[2],
        thr, leak, 3, OC[3]);
    { float** tmp = src; src = dst; dst = tmp; }

    // L4: 128->256 @8x8. blocks = 4*128 = 512
    conv_mid3_kernel<2, 8, 0, 128, 8><<<BATCH * (OC[4] / 2), 512, 0, stream>>>(
        src[0], src[1], src[2], convw[4], dst[0], dst[1], dst[2],
        thr, leak, 4, OC[4]);
    { float** tmp = src; src = dst; dst = tmp; }

    // L5: 256->256 @8x8. blocks = 512
    conv_mid3_kernel<2, 8, 0, 256, 8><<<BATCH * (OC[5] / 2), 512, 0, stream>>>(
        src[0], src[1], src[2], convw[5], dst[0], dst[1], dst[2],
        thr, leak, 5, OC[5]);
    { float** tmp = src; src = dst; dst = tmp; }

    // L6: 256->256 @8x8, pool. blocks = 512
    conv_mid3_kernel<2, 8, 1, 256, 8><<<BATCH * (OC[6] / 2), 512, 0, stream>>>(
        src[0], src[1], src[2], convw[6], dst[0], dst[1], dst[2],
        thr, leak, 6, OC[6]);
    { float** tmp = src; src = dst; dst = tmp; }

    // L7-L12: conv_small4_3
    for (int i = 7; i <= 12; ++i) {
        if (i == 7)
            conv_small4_3_kernel<4, 4, 0><<<OC[i], 256, 0, stream>>>(
                src[0], src[1], src[2], convw[i], dst[0], dst[1], dst[2],
                thr, leak, i, IC[i], OC[i]);
        else if (i == 8)
            conv_small4_3_kernel<4, 8, 0><<<OC[i], 512, 0, stream>>>(
                src[0], src[1], src[2], convw[i], dst[0], dst[1], dst[2],
                thr, leak, i, IC[i], OC[i]);
        else if (i == 9)
            conv_small4_3_kernel<4, 8, 1><<<OC[i], 512, 0, stream>>>(
                src[0], src[1], src[2], convw[i], dst[0], dst[1], dst[2],
                thr, leak, i, IC[i], OC[i]);
        else
            conv_small4_3_kernel<2, 8, 0><<<OC[i], 512, 0, stream>>>(
                src[0], src[1], src[2], convw[i], dst[0], dst[1], dst[2],
                thr, leak, i, IC[i], OC[i]);
        float** tmp = src; src = dst; dst = tmp;
    }

    // fc0, fc1 (LIF), fc2 (logit accumulate over t)
    fc_lif3_kernel<<<(4096 * 64) / 256, 256, 0, stream>>>(
        src[0], src[1], src[2], fc0, dst[0], dst[1], dst[2],
        thr, leak, 13, 2048, 4096);
    { float** tmp = src; src = dst; dst = tmp; }

    fc_lif3_kernel<<<(4096 * 64) / 256, 256, 0, stream>>>(
        src[0], src[1], src[2], fc1, dst[0], dst[1], dst[2],
        thr, leak, 14, 4096, 4096);
    { float** tmp = src; src = dst; dst = tmp; }

    fc2_acc3_kernel<<<BATCH * 10, 64, 0, stream>>>(
        src[0], src[1], src[2], fc2, (float*)d_out, 4096, 10);
}

// Round 9
// 641.433 us; speedup vs baseline: 1.2221x; 1.0791x over previous
//
#include <hip/hip_runtime.h>

// VGG16-A spiking NN, multi-compartment LIF (K=2), T=3, B=4, fp32.
// Round 15: halo-padded + t-packed activation layout for L0-L6.
//  - r14 post-mortem: LDS weight staging regressed L5/L6 (wave-uniform
//    global weight loads were already cheap). The real cost: 27 gathered
//    load addr-adds + 27 cndmask per ic vs 54 FMA (85% overhead VALU).
//  - Activations between conv layers now live in (W+2)x(W+2) padded
//    planes of float4 cells {t0,t1,t2,pad}: 9 unmasked float4 loads at
//    compile-time immediate offsets per ic; one pointer bump; no masks.
//  - Halo zeroed by ch==0 blocks in each epilogue (next dispatch reads it).
//  - L6 writes plain layout; small4 / fc chain unchanged (r11-verified).
//  - Weights: r11-style direct global loads (wave-uniform). No LDS in
//    the main loop. Arithmetic order bit-identical to r11.

#define BATCH 4

__device__ __forceinline__ float lif_update(float mem_in, float syn, float thr,
                                            float leak, float* mem_out) {
    float m = leak * mem_in + syn;
    float val = 0.f;
    if ((m / thr - 1.f > 0.f) && (1.f - m / (2.f * thr) >= 0.f)) val += 1.f;
    if ((m / (2.f * thr) - 1.f > 0.f) && (1.f - m / (4.f * thr) >= 0.f)) val += 2.f;
    *mem_out = m - thr * val;
    return val;
}

// Layer 0 (IC=3, OC=64, 32x32): conv once (timestep-invariant), 3 LIF
// steps in registers, write padded t-packed float4 cell. Threads with
// idx < 33792 also zero the halo ring (4*64 planes x 132 cells).
__global__ void conv_lif0_pad_kernel(const float* __restrict__ in,
                                     const float* __restrict__ w,
                                     float4* __restrict__ out4,
                                     const float* __restrict__ thr_v,
                                     const float* __restrict__ leak_v,
                                     int n) {
    constexpr int H = 32, W = 32, IC = 3, OC = 64;
    constexpr int PW = 34, PP = 34 * 34;
    int idx = blockIdx.x * blockDim.x + threadIdx.x;
    if (idx >= n) return;
    int x  = idx % W;
    int y  = (idx / W) % H;
    int oc = (idx / (W * H)) % OC;
    int b  = idx / (W * H * OC);

    const float* wp = w + (size_t)oc * IC * 9;
    const float* ip = in + (size_t)b * IC * H * W;

    float syn = 0.f;
    for (int ic = 0; ic < IC; ++ic) {
        const float* ipc = ip + (size_t)ic * H * W;
        const float* wpc = wp + ic * 9;
#pragma unroll
        for (int ky = 0; ky < 3; ++ky) {
            int yy = y + ky - 1;
            if (yy < 0 || yy >= H) continue;
#pragma unroll
            for (int kx = 0; kx < 3; ++kx) {
                int xx = x + kx - 1;
                if (xx < 0 || xx >= W) continue;
                syn = fmaf(ipc[yy * W + xx], wpc[ky * 3 + kx], syn);
            }
        }
    }
    float thr = thr_v[0], leak = leak_v[0];
    float m = 0.f;
    float v0 = lif_update(m, syn, thr, leak, &m);
    float v1 = lif_update(m, syn, thr, leak, &m);
    float v2 = lif_update(m, syn, thr, leak, &m);
    size_t cell = (size_t)(b * OC + oc) * PP + (size_t)(y + 1) * PW + (x + 1);
    out4[cell] = make_float4(v0, v1, v2, 0.f);

    // halo ring zero: 256 planes x 132 cells
    if (idx < 256 * 132) {
        int bc = idx / 132;
        int c  = idx % 132;
        int row, col;
        if (c < 34) { row = 0; col = c; }
        else if (c < 68) { row = 33; col = c - 34; }
        else { int d = c - 68; row = 1 + (d >> 1); col = (d & 1) * 33; }
        out4[(size_t)bc * PP + (size_t)row * PW + col] = make_float4(0.f, 0.f, 0.f, 0.f);
    }
}

// 9 taps as float4 cells at compile-time offsets from lane base.
template <int PW>
__device__ __forceinline__ void pad_load9(float4 tv[9],
                                          const float4* __restrict__ lp) {
#pragma unroll
    for (int ky = 0; ky < 3; ++ky)
#pragma unroll
        for (int kx = 0; kx < 3; ++kx) tv[ky * 3 + kx] = lp[ky * PW + kx];
}

// FMA 3 timesteps x OCT ocs for one ic; weights direct from global
// (wave-uniform address).
template <int OCT, int ICT>
__device__ __forceinline__ void pad_fma3(const float4 tv[9],
                                         const float* __restrict__ wp,
                                         float acc[3][OCT]) {
#pragma unroll
    for (int q = 0; q < OCT; ++q) {
        const float* wq = wp + (size_t)q * ICT * 9;
        float wr[9];
#pragma unroll
        for (int k = 0; k < 9; ++k) wr[k] = wq[k];
#pragma unroll
        for (int k = 0; k < 9; ++k) {
            acc[0][q] = fmaf(tv[k].x, wr[k], acc[0][q]);
            acc[1][q] = fmaf(tv[k].y, wr[k], acc[1][q]);
            acc[2][q] = fmaf(tv[k].z, wr[k], acc[2][q]);
        }
    }
}

// Layers 1-6, 3 timesteps fused, padded t-packed input. Block = NW waves.
// blockIdx -> (b, chunk, oc-group). Wave wv covers its ICT/NW channels
// with 2-ic ping-pong prefetch. LDS reduce; in-register membrane LIF;
// POOL: fused 2x2 avg-pool. PLAIN: write plain layout (L6 -> small4).
// Else write padded t-packed + zero halo (ch==0 blocks).
template <int OCT, int NW, int POOL, int PLAIN, int ICT, int W_>
__global__ __launch_bounds__(NW * 64)
void conv_pad3_kernel(const float4* __restrict__ in4,
                      const float* __restrict__ w,
                      float4* __restrict__ out4,
                      float* __restrict__ out0,
                      float* __restrict__ out1,
                      float* __restrict__ out2,
                      const float* __restrict__ thr_v,
                      const float* __restrict__ leak_v,
                      int layer, int OC) {
    constexpr int PW = W_ + 2;
    constexpr int PP = PW * PW;
    constexpr int CHUNKS = (W_ * W_) / 64;
    constexpr int RPW = 64 / W_;
    constexpr int ICPW = ICT / NW;
    static_assert((ICPW & 1) == 0, "icpw must be even");

    int tid = threadIdx.x;
    int lane = tid & 63;
    int wv = tid >> 6;  // 0..NW-1
    int ocg = OC / OCT;
    int bid = blockIdx.x;
    int g  = bid % ocg;
    int ch = (bid / ocg) % CHUNKS;
    int b  = bid / (ocg * CHUNKS);
    int y = ch * RPW + lane / W_;
    int x = lane % W_;
    int oc0 = g * OCT;

    const float4* lp = in4 + ((size_t)b * ICT + (size_t)wv * ICPW) * PP
                       + (size_t)y * PW + x;
    const float* wbase = w + ((size_t)oc0 * ICT + (size_t)wv * ICPW) * 9;

    float acc[3][OCT];
#pragma unroll
    for (int t = 0; t < 3; ++t)
#pragma unroll
        for (int q = 0; q < OCT; ++q) acc[t][q] = 0.f;

    float4 tva[9], tvb[9];
    pad_load9<PW>(tva, lp);

    for (int i = 0; i < ICPW; i += 2) {
        pad_load9<PW>(tvb, lp + PP);
        pad_fma3<OCT, ICT>(tva, wbase + (size_t)i * 9, acc);
        const float4* lpn = (i + 2 < ICPW) ? lp + 2 * PP : lp;
        pad_load9<PW>(tva, lpn);
        pad_fma3<OCT, ICT>(tvb, wbase + (size_t)(i + 1) * 9, acc);
        lp += 2 * PP;
    }

    __shared__ float red[NW][OCT][64];
    float thr = thr_v[layer], leak = leak_v[layer];
    float mem_reg = 0.f;  // membrane carried in-register across timesteps
    int eq = tid >> 6, ep = tid & 63;
    float4 myv = make_float4(0.f, 0.f, 0.f, 0.f);

#pragma unroll
    for (int t = 0; t < 3; ++t) {
        __syncthreads();
#pragma unroll
        for (int q = 0; q < OCT; ++q) red[wv][q][lane] = acc[t][q];
        __syncthreads();
        if (tid < OCT * 64) {
            float sum = 0.f;
#pragma unroll
            for (int q = 0; q < NW; ++q) sum += red[q][eq][ep];
            float val = lif_update(mem_reg, sum, thr, leak, &mem_reg);
            if (t == 0) myv.x = val;
            else if (t == 1) myv.y = val;
            else myv.z = val;
        }
    }

    if (!POOL) {
        // unpooled padded write: same plane geometry as input
        if (tid < OCT * 64) {
            int yo = ch * RPW + ep / W_;
            int xo = ep % W_;
            size_t cell = (size_t)(b * OC + oc0 + eq) * PP
                          + (size_t)(yo + 1) * PW + (xo + 1);
            out4[cell] = myv;
        }
    } else {
        __shared__ float4 vals4[OCT][64];
        if (tid < OCT * 64) vals4[eq][ep] = myv;
        __syncthreads();
        constexpr int Wo = W_ / 2;
        if (tid < OCT * 16) {
            int q = tid >> 4, s = tid & 15;
            int pr = s / Wo, pc = s % Wo;
            float4 a = vals4[q][(2 * pr) * W_ + 2 * pc];
            float4 bb = vals4[q][(2 * pr) * W_ + 2 * pc + 1];
            float4 c = vals4[q][(2 * pr + 1) * W_ + 2 * pc];
            float4 d = vals4[q][(2 * pr + 1) * W_ + 2 * pc + 1];
            float4 pv;
            pv.x = 0.25f * (a.x + bb.x + c.x + d.x);
            pv.y = 0.25f * (a.y + bb.y + c.y + d.y);
            pv.z = 0.25f * (a.z + bb.z + c.z + d.z);
            pv.w = 0.f;
            int prg = ch * (RPW >> 1) + pr;
            if (PLAIN) {
                size_t pidx = ((size_t)(b * OC + oc0 + q) * Wo + prg) * Wo + pc;
                out0[pidx] = pv.x;
                out1[pidx] = pv.y;
                out2[pidx] = pv.z;
            } else {
                constexpr int PWo = Wo + 2, PPo = PWo * PWo;
                size_t cell = (size_t)(b * OC + oc0 + q) * PPo
                              + (size_t)(prg + 1) * PWo + (pc + 1);
                out4[cell] = pv;
            }
        }
    }

    // halo zero for padded outputs (one chunk's blocks per (b,g))
    if (!PLAIN && ch == 0) {
        constexpr int S = POOL ? W_ / 2 : W_;
        constexpr int PWo = S + 2, PPo = PWo * PWo;
        constexpr int NH = 4 * S + 4;
        for (int s2 = tid; s2 < OCT * NH; s2 += NW * 64) {
            int q = s2 / NH, c = s2 % NH;
            int row, col;
            if (c < S + 2) { row = 0; col = c; }
            else if (c < 2 * (S + 2)) { row = S + 1; col = c - (S + 2); }
            else { int d2 = c - 2 * (S + 2); row = 1 + (d2 >> 1); col = (d2 & 1) * (S + 1); }
            out4[(size_t)(b * OC + oc0 + q) * PPo + (size_t)row * PWo + col] =
                make_float4(0.f, 0.f, 0.f, 0.f);
        }
    }
}

// Layers 7-12 (4x4 / 2x2 planes), 3 timesteps fused (sequential passes,
// membrane in-register). Block = NW waves, one oc per block. (r11-verified)
template <int S, int NW, int POOL>
__global__ __launch_bounds__(NW * 64)
void conv_small4_3_kernel(const float* __restrict__ in0,
                          const float* __restrict__ in1,
                          const float* __restrict__ in2,
                          const float* __restrict__ w,
                          float* __restrict__ out0,
                          float* __restrict__ out1,
                          float* __restrict__ out2,
                          const float* __restrict__ thr_v,
                          const float* __restrict__ leak_v,
                          int layer, int IC, int OC) {
    constexpr int SS = S * S;
    constexpr int M = 4 * SS;              // 64 (S=4) or 16 (S=2)
    constexpr int LOG2M = (S == 4) ? 6 : 4;
    int tid = threadIdx.x;
    int lane = tid & 63;
    int wv = tid >> 6;  // 0..NW-1
    int oc = blockIdx.x;

    const float* const ins[3] = {in0, in1, in2};
    float* const outs[3] = {out0, out1, out2};
    const float* wrow = w + (size_t)oc * IC * 9;

    __shared__ float red[NW][M];
    __shared__ float pvs[M];
    float thr = thr_v[layer], leak = leak_v[layer];
    float mem_reg = 0.f;  // for tid < M

#pragma unroll
    for (int t = 0; t < 3; ++t) {
        const float* inb = ins[t];
        float acc[M];
#pragma unroll
        for (int i = 0; i < M; ++i) acc[i] = 0.f;

        for (int ic = lane + (wv << 6); ic < IC; ic += NW * 64) {
            const float* wp = wrow + (size_t)ic * 9;
            float wvv[9];
#pragma unroll
            for (int k = 0; k < 9; ++k) wvv[k] = wp[k];
#pragma unroll
            for (int b = 0; b < 4; ++b) {
                const float4* ip = (const float4*)(inb + (size_t)(b * IC + ic) * SS);
                float pv[SS];
#pragma unroll
                for (int q = 0; q < SS / 4; ++q) {
                    float4 t4 = ip[q];
                    pv[4 * q + 0] = t4.x;
                    pv[4 * q + 1] = t4.y;
                    pv[4 * q + 2] = t4.z;
                    pv[4 * q + 3] = t4.w;
                }
#pragma unroll
                for (int y = 0; y < S; ++y)
#pragma unroll
                    for (int x = 0; x < S; ++x) {
                        float a = acc[b * SS + y * S + x];
#pragma unroll
                        for (int ky = 0; ky < 3; ++ky) {
                            int yy = y + ky - 1;
                            if (yy < 0 || yy >= S) continue;
#pragma unroll
                            for (int kx = 0; kx < 3; ++kx) {
                                int xx = x + kx - 1;
                                if (xx < 0 || xx >= S) continue;
                                a = fmaf(pv[yy * S + xx], wvv[ky * 3 + kx], a);
                            }
                        }
                        acc[b * SS + y * S + x] = a;
                    }
            }
        }

        // per-wave transpose-reduce: M accs across 64 lanes -> 1 per lane
#pragma unroll
        for (int step = 0; step < LOG2M; ++step) {
            const int offx = 1 << step;
            const int half = M >> (step + 1);
            const bool hi = (lane & offx) != 0;
#pragma unroll
            for (int i = 0; i < half; ++i) {
                float sent = hi ? acc[i] : acc[i + half];
                float got = __shfl_xor(sent, offx);
                acc[i] = (hi ? acc[i + half] : acc[i]) + got;
            }
        }
        float sum = acc[0];
#pragma unroll
        for (int offx = M; offx < 64; offx <<= 1) sum += __shfl_xor(sum, offx);

        __syncthreads();  // protect red/pvs from previous timestep's readers
        int o = (int)(__brev((unsigned)(lane & (M - 1))) >> (32 - LOG2M));
        if (lane < M) red[wv][o] = sum;
        __syncthreads();

        if (tid < M) {
            float tot = 0.f;
#pragma unroll
            for (int q = 0; q < NW; ++q) tot += red[q][tid];
            int b = tid / SS, p = tid % SS;
            float val = lif_update(mem_reg, tot, thr, leak, &mem_reg);
            if (POOL) {
                pvs[tid] = val;
            } else {
                size_t idx = (size_t)(b * OC + oc) * SS + p;
                outs[t][idx] = val;
            }
        }
        if (POOL) {
            __syncthreads();
            constexpr int Sh = S / 2, SSh = Sh * Sh;
            if (tid < 4 * SSh) {
                int b = tid / SSh, q = tid % SSh;
                int pr = q / Sh, pc = q % Sh;
                float pv = 0.25f * (pvs[b * SS + (2 * pr) * S + 2 * pc] +
                                    pvs[b * SS + (2 * pr) * S + 2 * pc + 1] +
                                    pvs[b * SS + (2 * pr + 1) * S + 2 * pc] +
                                    pvs[b * SS + (2 * pr + 1) * S + 2 * pc + 1]);
                outs[t][((size_t)(b * OC + oc) * Sh + pr) * Sh + pc] = pv;
            }
        }
    }
}

// Wave-per-output-neuron FC+LIF, 3 timesteps fused: weight row read ONCE,
// 12 accumulators (3t x 4b), membrane chain at lane 0.
__global__ void fc_lif3_kernel(const float* __restrict__ in0,
                               const float* __restrict__ in1,
                               const float* __restrict__ in2,
                               const float* __restrict__ w,
                               float* __restrict__ out0,
                               float* __restrict__ out1,
                               float* __restrict__ out2,
                               const float* __restrict__ thr_v,
                               const float* __restrict__ leak_v,
                               int layer, int Kd, int N) {
    int wave = (blockIdx.x * blockDim.x + threadIdx.x) >> 6;
    int lane = threadIdx.x & 63;
    if (wave >= N) return;
    int j = wave;
    int K4 = Kd >> 2;
    const float4* wp = (const float4*)(w + (size_t)j * Kd);
    const float4* ip[3] = {(const float4*)in0, (const float4*)in1, (const float4*)in2};
    float* const outs[3] = {out0, out1, out2};

    float a[3][4];
#pragma unroll
    for (int t = 0; t < 3; ++t)
#pragma unroll
        for (int b = 0; b < 4; ++b) a[t][b] = 0.f;

    for (int k = lane; k < K4; k += 64) {
        float4 wv = wp[k];
#pragma unroll
        for (int t = 0; t < 3; ++t)
#pragma unroll
            for (int b = 0; b < 4; ++b) {
                float4 v = ip[t][b * K4 + k];
                a[t][b] = fmaf(wv.x, v.x, fmaf(wv.y, v.y,
                          fmaf(wv.z, v.z, fmaf(wv.w, v.w, a[t][b]))));
            }
    }
#pragma unroll
    for (int t = 0; t < 3; ++t)
#pragma unroll
        for (int b = 0; b < 4; ++b)
#pragma unroll
            for (int off = 32; off > 0; off >>= 1)
                a[t][b] += __shfl_xor(a[t][b], off);

    if (lane == 0) {
        float thr = thr_v[layer], leak = leak_v[layer];
#pragma unroll
        for (int b = 0; b < BATCH; ++b) {
            float m = 0.f;
#pragma unroll
            for (int t = 0; t < 3; ++t) {
                float val = lif_update(m, a[t][b], thr, leak, &m);
                outs[t][(size_t)b * N + j] = val;
            }
        }
    }
}

// One 64-thread block per (b, label). logits = sum_t in_t[b,:] . w[l,:]
__global__ void fc2_acc3_kernel(const float* __restrict__ in0,
                                const float* __restrict__ in1,
                                const float* __restrict__ in2,
                                const float* __restrict__ w,
                                float* __restrict__ logits,
                                int Kd, int L) {
    int o = blockIdx.x;
    int l = o % L;
    int b = o / L;
    int K4 = Kd >> 2;
    const float4* ip[3] = {(const float4*)(in0 + (size_t)b * Kd),
                           (const float4*)(in1 + (size_t)b * Kd),
                           (const float4*)(in2 + (size_t)b * Kd)};
    const float4* wp = (const float4*)(w + (size_t)l * Kd);
    float st[3] = {0.f, 0.f, 0.f};
    for (int k = threadIdx.x; k < K4; k += 64) {
        float4 wv = wp[k];
#pragma unroll
        for (int t = 0; t < 3; ++t) {
            float4 iv = ip[t][k];
            st[t] = fmaf(iv.x, wv.x, fmaf(iv.y, wv.y,
                    fmaf(iv.z, wv.z, fmaf(iv.w, wv.w, st[t]))));
        }
    }
#pragma unroll
    for (int t = 0; t < 3; ++t)
#pragma unroll
        for (int off = 32; off > 0; off >>= 1) st[t] += __shfl_xor(st[t], off);
    if (threadIdx.x == 0) logits[o] = (st[0] + st[1]) + st[2];
}

extern "C" void kernel_launch(void* const* d_in, const int* in_sizes, int n_in,
                              void* d_out, int out_size, void* d_ws, size_t ws_size,
                              hipStream_t stream) {
    const float* x = (const float*)d_in[0];
    const float* convw[13];
    for (int i = 0; i < 13; ++i) convw[i] = (const float*)d_in[1 + i];
    const float* fc0 = (const float*)d_in[14];
    const float* fc1 = (const float*)d_in[15];
    const float* fc2 = (const float*)d_in[16];
    const float* thr = (const float*)d_in[17];
    const float* leak = (const float*)d_in[18];

    static const int IC[13] = {3, 64, 64, 128, 128, 256, 256, 256, 512, 512, 512, 512, 512};
    static const int OC[13] = {64, 64, 128, 128, 256, 256, 256, 512, 512, 512, 512, 512, 512};

    float* wsf = (float*)d_ws;
    // two padded t-packed buffers (float4 cells), max 295936 cells (L0 out)
    float4* P0 = (float4*)wsf;
    float4* P1 = P0 + 300000;
    float* base = wsf + (size_t)2 * 300000 * 4;
    float* A[3];
    float* B[3];
    for (int i = 0; i < 3; ++i) { A[i] = base + (size_t)i * 65536; }
    for (int i = 0; i < 3; ++i) { B[i] = base + (size_t)(3 + i) * 65536; }

    // L0: conv once + 3 in-register LIF steps -> P0 (padded, t-packed)
    {
        int n = BATCH * 64 * 32 * 32;
        conv_lif0_pad_kernel<<<(n + 255) / 256, 256, 0, stream>>>(
            x, convw[0], P0, thr, leak, n);
    }

    // L1: 64->64 @32x32, pool. blocks = 4b * 16ch * 16g = 1024
    conv_pad3_kernel<4, 8, 1, 0, 64, 32><<<BATCH * 16 * (OC[1] / 4), 512, 0, stream>>>(
        P0, convw[1], P1, nullptr, nullptr, nullptr, thr, leak, 1, OC[1]);

    // L2: 64->128 @16x16. blocks = 4 * 4 * 32 = 512
    conv_pad3_kernel<4, 8, 0, 0, 64, 16><<<BATCH * 4 * (OC[2] / 4), 512, 0, stream>>>(
        P1, convw[2], P0, nullptr, nullptr, nullptr, thr, leak, 2, OC[2]);

    // L3: 128->128 @16x16, pool. blocks = 512
    conv_pad3_kernel<4, 8, 1, 0, 128, 16><<<BATCH * 4 * (OC[3] / 4), 512, 0, stream>>>(
        P0, convw[3], P1, nullptr, nullptr, nullptr, thr, leak, 3, OC[3]);

    // L4: 128->256 @8x8. blocks = 4 * 128 = 512
    conv_pad3_kernel<2, 8, 0, 0, 128, 8><<<BATCH * (OC[4] / 2), 512, 0, stream>>>(
        P1, convw[4], P0, nullptr, nullptr, nullptr, thr, leak, 4, OC[4]);

    // L5: 256->256 @8x8. blocks = 512
    conv_pad3_kernel<2, 8, 0, 0, 256, 8><<<BATCH * (OC[5] / 2), 512, 0, stream>>>(
        P0, convw[5], P1, nullptr, nullptr, nullptr, thr, leak, 5, OC[5]);

    // L6: 256->256 @8x8, pool -> PLAIN layout for small4 chain
    conv_pad3_kernel<2, 8, 1, 1, 256, 8><<<BATCH * (OC[6] / 2), 512, 0, stream>>>(
        P1, convw[6], P0 /*unused*/, A[0], A[1], A[2], thr, leak, 6, OC[6]);

    float** src = A;
    float** dst = B;

    // L7-L12: conv_small4_3
    for (int i = 7; i <= 12; ++i) {
        if (i == 7)
            conv_small4_3_kernel<4, 4, 0><<<OC[i], 256, 0, stream>>>(
                src[0], src[1], src[2], convw[i], dst[0], dst[1], dst[2],
                thr, leak, i, IC[i], OC[i]);
        else if (i == 8)
            conv_small4_3_kernel<4, 8, 0><<<OC[i], 512, 0, stream>>>(
                src[0], src[1], src[2], convw[i], dst[0], dst[1], dst[2],
                thr, leak, i, IC[i], OC[i]);
        else if (i == 9)
            conv_small4_3_kernel<4, 8, 1><<<OC[i], 512, 0, stream>>>(
                src[0], src[1], src[2], convw[i], dst[0], dst[1], dst[2],
                thr, leak, i, IC[i], OC[i]);
        else
            conv_small4_3_kernel<2, 8, 0><<<OC[i], 512, 0, stream>>>(
                src[0], src[1], src[2], convw[i], dst[0], dst[1], dst[2],
                thr, leak, i, IC[i], OC[i]);
        float** tmp = src; src = dst; dst = tmp;
    }

    // fc0, fc1 (LIF), fc2 (logit accumulate over t)
    fc_lif3_kernel<<<(4096 * 64) / 256, 256, 0, stream>>>(
        src[0], src[1], src[2], fc0, dst[0], dst[1], dst[2],
        thr, leak, 13, 2048, 4096);
    { float** tmp = src; src = dst; dst = tmp; }

    fc_lif3_kernel<<<(4096 * 64) / 256, 256, 0, stream>>>(
        src[0], src[1], src[2], fc1, dst[0], dst[1], dst[2],
        thr, leak, 14, 4096, 4096);
    { float** tmp = src; src = dst; dst = tmp; }

    fc2_acc3_kernel<<<BATCH * 10, 64, 0, stream>>>(
        src[0], src[1], src[2], fc2, (float*)d_out, 4096, 10);
}